// Round 5
// baseline (466.132 us; speedup 1.0000x reference)
//
#include <hip/hip_runtime.h>

typedef unsigned short u16;
typedef __attribute__((ext_vector_type(8))) short bf16x8;
typedef __attribute__((ext_vector_type(4))) float f32x4;
typedef __attribute__((ext_vector_type(16))) float f32x16;
typedef __attribute__((ext_vector_type(4))) unsigned short u16x4;

#define DM 1024

__device__ __forceinline__ float bf2f(u16 u){
  union { unsigned int i; float f; } v; v.i = ((unsigned int)u)<<16; return v.f;
}
__device__ __forceinline__ u16 f2bf(float f){
  unsigned int x = __float_as_uint(f);
  return (u16)((x + 0x7FFFu + ((x>>16)&1u)) >> 16);   // RNE, finite inputs only
}

// ---------------- K0: ternary-quantize the 4 weight matrices ----------------
__global__ __launch_bounds__(256)
void quantize_w(const float* __restrict__ W0, const float* __restrict__ W1,
                const float* __restrict__ W2, const float* __restrict__ W3,
                u16* __restrict__ wq, float* __restrict__ wsc)
{
  const int gr   = blockIdx.x*4 + (threadIdx.x>>6);
  const int lane = threadIdx.x & 63;
  const int mat  = gr >> 10, row = gr & 1023;
  const float* W = (mat==0)?W0:(mat==1)?W1:(mat==2)?W2:W3;
  const float* wr = W + (size_t)row*DM;
  float4 v[4]; float s = 0.f;
  #pragma unroll
  for (int c=0;c<4;c++){
    v[c] = *(const float4*)&wr[c*256 + lane*4];
    s += fabsf(v[c].x)+fabsf(v[c].y)+fabsf(v[c].z)+fabsf(v[c].w);
  }
  #pragma unroll
  for (int off=32; off; off>>=1) s += __shfl_down(s, off);
  s = __shfl(s, 0);
  const float scale = fmaxf(s*(1.f/1024.f), 1e-5f);
  if (lane==0) wsc[gr] = scale;
  u16* wo = wq + (size_t)gr*DM;
  #pragma unroll
  for (int c=0;c<4;c++){
    u16x4 q;
    q[0] = f2bf(fminf(fmaxf(rintf(v[c].x/scale),-1.f),1.f));
    q[1] = f2bf(fminf(fmaxf(rintf(v[c].y/scale),-1.f),1.f));
    q[2] = f2bf(fminf(fmaxf(rintf(v[c].z/scale),-1.f),1.f));
    q[3] = f2bf(fminf(fmaxf(rintf(v[c].w/scale),-1.f),1.f));
    *(u16x4*)&wo[c*256 + lane*4] = q;
  }
}

// ---------------- K1: x f32 -> bf16 ----------------
__global__ void cvt_x(const float* __restrict__ x, u16* __restrict__ xb){
  const int i = (blockIdx.x*256 + threadIdx.x)*4;
  float4 v = *(const float4*)&x[i];
  u16x4 o; o[0]=f2bf(v.x); o[1]=f2bf(v.y); o[2]=f2bf(v.z); o[3]=f2bf(v.w);
  *(u16x4*)&xb[i] = o;
}

// ---------------- K2/K6: 256x256 GEMM, BK=64, 32x32x16 MFMA, 4-phase rotation ------
// 8 waves (2M x 4N), per-wave C = 128x64 = 4 m-frags x 2 n-frags of 32x32.
// Per tile: p0{read B(8)+A-m1(4); stage A(t+1)->sA[c^1]; WL4; 8 MFMA m0}
//           p1{read A-m2; stage B(t+2)q01->sB[c]; WL4; 8 MFMA m1}
//           p2{read A-m3; stage B(t+2)q23; WL4; 8 MFMA m2; VM4}
//           p3{read A(t+1)-m0 from sA[c^1]; WL4; 8 MFMA m3}   (1 barrier per phase)
// vmcnt(4) once per tile at p2-end (retires A(t+1)+B(t+1); leaves B(t+2) in flight).
// XOR swizzle (row&7)<<4 on stage source + ds_read (involution).

#define SB0 __builtin_amdgcn_sched_barrier(0)
#define WL4  do{ asm volatile("s_waitcnt lgkmcnt(4)" ::: "memory"); SB0; }while(0)
#define WL0  do{ asm volatile("s_waitcnt lgkmcnt(0)" ::: "memory"); SB0; }while(0)
#define VM4  do{ asm volatile("s_waitcnt vmcnt(4)" ::: "memory"); SB0; }while(0)
#define VM0  do{ asm volatile("s_waitcnt vmcnt(0)" ::: "memory"); SB0; }while(0)
#define BARR do{ SB0; __builtin_amdgcn_s_barrier(); SB0; }while(0)

#define STG(gB, off, T, Q, buf) \
  __builtin_amdgcn_global_load_lds( \
    (const __attribute__((address_space(1))) void*)((const char*)(gB) + (off) + (Q)*131072 + (size_t)(T)*128), \
    (__attribute__((address_space(3))) void*)((char*)(buf) + ldst + (Q)*8192), 16, 0, 0)

#define RD(base, off) (*(const bf16x8*)((const char*)(base) + (off)))

#define RDA4(DST, BASE, ROWOFF) \
  DST[0]=RD(BASE,(ROWOFF)+koff0); DST[1]=RD(BASE,(ROWOFF)+koff1); \
  DST[2]=RD(BASE,(ROWOFF)+koff2); DST[3]=RD(BASE,(ROWOFF)+koff3);

#define MFMA8(AF, MI) \
  __builtin_amdgcn_s_setprio(1); \
  _Pragma("unroll") \
  for (int kk=0; kk<4; ++kk){ \
    acc[MI][0] = __builtin_amdgcn_mfma_f32_32x32x16_bf16(AF[kk], bF[0][kk], acc[MI][0], 0,0,0); \
    acc[MI][1] = __builtin_amdgcn_mfma_f32_32x32x16_bf16(AF[kk], bF[1][kk], acc[MI][1], 0,0,0); \
  } \
  __builtin_amdgcn_s_setprio(0)

// generic tile: with literal T all conditions fold at compile time
#define TILE(T, C, FULL) { \
  const char* la  = (const char*)sA[C]; \
  const char* lb  = (const char*)sB[C]; \
  const char* lnA = (const char*)sA[(C)^1]; \
  /* p0 */ \
  RDA4(bF[0], lb, brow) \
  RDA4(bF[1], lb, brow+4096) \
  RDA4(aA, la, arow+4096) \
  if (FULL || (T)+1<nt){ STG(Ag,aoff,(T)+1,0,sA[(C)^1]); STG(Ag,aoff,(T)+1,1,sA[(C)^1]); \
                         STG(Ag,aoff,(T)+1,2,sA[(C)^1]); STG(Ag,aoff,(T)+1,3,sA[(C)^1]); } \
  WL4; MFMA8(aB, 0); BARR; \
  /* p1 */ \
  RDA4(aB, la, arow+2*4096) \
  if (FULL || (T)+2<nt){ STG(Bg,boff,(T)+2,0,sB[C]); STG(Bg,boff,(T)+2,1,sB[C]); } \
  WL4; MFMA8(aA, 1); BARR; \
  /* p2 */ \
  RDA4(aA, la, arow+3*4096) \
  if (FULL || (T)+2<nt){ STG(Bg,boff,(T)+2,2,sB[C]); STG(Bg,boff,(T)+2,3,sB[C]); } \
  WL4; MFMA8(aB, 2); SB0; \
  if (FULL || (T)<nt-2) { VM4; } else if ((T)==nt-2) { VM0; } \
  BARR; \
  /* p3 */ \
  if (FULL || (T)<nt-1){ RDA4(aB, lnA, arow) WL4; } else { WL0; } \
  MFMA8(aA, 3); BARR; \
}

template<int MODE>
__global__ __launch_bounds__(512, 2)
void gemm_p(const u16* __restrict__ Ag, const u16* __restrict__ Bg,
            const float* __restrict__ bscale,
            u16* __restrict__ o_r, u16* __restrict__ o_k, u16* __restrict__ o_v,
            float* __restrict__ o_f)
{
  __shared__ u16 sA[2][256*64];
  __shared__ u16 sB[2][256*64];
  const int tid = threadIdx.x, wave = tid>>6, lane = tid&63;
  const int ll = lane&31, lh = lane>>5;
  const int wm = wave>>2, wn = wave&3;
  const int bm0 = blockIdx.x*256, bn0 = blockIdx.y*256;
  constexpr int nt = 16;                        // K = 1024 / 64

  // staging addresses
  const int r8   = lane>>3;
  const int scol = ((lane&7)<<4) ^ (r8<<4);     // pre-swizzled source col (bytes)
  const size_t aoff = (size_t)(bm0 + wave*8 + r8)*2048 + scol;
  const size_t boff = (size_t)(bn0 + wave*8 + r8)*2048 + scol;
  const int ldst = wave*1024;                   // LDS dest base (+q*8192)
  // ds_read addresses: row = base + ll ; k-byte = (kk*32 + lh*16) ^ ((ll&7)<<4)
  const int S = (ll&7)<<4;
  const int koff0 = (0*32 + (lh<<4)) ^ S;
  const int koff1 = (1*32 + (lh<<4)) ^ S;
  const int koff2 = (2*32 + (lh<<4)) ^ S;
  const int koff3 = (3*32 + (lh<<4)) ^ S;
  const int arow = (wm*128 + ll)*128;           // + m*4096
  const int brow = (wn*64  + ll)*128;           // + n*4096

  f32x16 acc[4][2];
  #pragma unroll
  for (int i=0;i<4;i++)
    #pragma unroll
    for (int j=0;j<2;j++)
      acc[i][j] = (f32x16){0,0,0,0,0,0,0,0,0,0,0,0,0,0,0,0};

  bf16x8 bF[2][4], aA[4], aB[4];

  // prologue: stage A(0),B(0)->bufs[0]; B(1)->sB[1]; then read A(0)-m0
  #pragma unroll
  for (int q=0;q<4;q++){ STG(Ag, aoff, 0, q, sA[0]); STG(Bg, boff, 0, q, sB[0]); }
  #pragma unroll
  for (int q=0;q<4;q++){ STG(Bg, boff, 1, q, sB[1]); }
  VM4;                                          // A(0),B(0) landed; B(1) in flight
  BARR;
  RDA4(aB, (const char*)sA[0], arow)            // A(0) m0 (p0's WL4 covers)

  for (int tp=0; tp<nt-2; tp+=2){               // t = 0..13: branch-free full tiles
    TILE(tp,   0, true)
    TILE(tp+1, 1, true)
  }
  TILE(14, 0, false)                            // stages A(15) only; VM0 at p2
  TILE(15, 1, false)                            // no stages; WL0 at p3

  // ---- epilogue: C/D 32x32: col=lane&31, row=(reg&3)+8*(reg>>2)+4*(lane>>5) ----
  #pragma unroll
  for (int m=0; m<4; ++m){
    #pragma unroll
    for (int n=0; n<2; ++n){
      const int col = bn0 + wn*64 + n*32 + ll;
      const float sc = bscale[col];
      const int rowb = bm0 + wm*128 + m*32 + lh*4;
      const f32x16 a = acc[m][n];
      if (MODE==0){
        const int seg = col>>10, d = col&1023;
        #pragma unroll
        for (int r=0;r<16;r++){
          const int row = rowb + (r&3) + 8*(r>>2);
          const float val = a[r]*sc;
          const size_t o = (size_t)row*DM + d;
          if (seg==0)      o_r[o] = f2bf(1.f/(1.f+expf(-val)));
          else if (seg==1) o_k[o] = f2bf(val);
          else             o_v[o] = f2bf(val);
        }
      } else {
        #pragma unroll
        for (int r=0;r<16;r++){
          const int row = rowb + (r&3) + 8*(r>>2);
          o_f[(size_t)row*DM + col] = a[r]*sc;
        }
      }
    }
  }
}

// ---------------- K3: per-chunk sums of k*v / max(exp(t*ld),1e-10), CH=32 ----------
__global__ __launch_bounds__(256)
void kv_phase1(const u16* __restrict__ kb, const u16* __restrict__ vb,
               const float* __restrict__ decay, float* __restrict__ part)
{
  const int c = blockIdx.x & 127, b = blockIdx.x >> 7;
  const int d0 = threadIdx.x*4;
  float ld[4]; f32x4 sum = {0.f,0.f,0.f,0.f};
  #pragma unroll
  for (int j=0;j<4;j++){
    const float dec = 1.f/(1.f+expf(-decay[d0+j]));
    ld[j] = logf(fmaxf(dec, 1e-7f));
  }
  for (int t=c*32; t<c*32+32; ++t){
    const size_t base = ((size_t)(b*4096 + t))*DM + d0;
    const u16x4 k4 = *(const u16x4*)&kb[base];
    const u16x4 v4 = *(const u16x4*)&vb[base];
    const float tf = (float)t;
    #pragma unroll
    for (int j=0;j<4;j++){
      const float e = expf(tf*ld[j]);                        // underflows to 0 like ref
      sum[j] += bf2f(k4[j])*bf2f(v4[j]) / fmaxf(e, 1e-10f);
    }
  }
  *(f32x4*)&part[((size_t)(b*128+c))*DM + d0] = sum;
}

// ---------------- K4: exclusive prefix over 128 chunk sums (8-wide pipelined) -------
__global__ void chunk_prefix(float* __restrict__ part){
  const int g = blockIdx.x*256 + threadIdx.x;  // 0..1023
  const int b = g >> 8, d0 = (g & 255)*4;
  f32x4 run = {0.f,0.f,0.f,0.f};
  for (int c8=0; c8<128; c8+=8){
    f32x4 v[8];
    #pragma unroll
    for (int i=0;i<8;i++)
      v[i] = *(const f32x4*)&part[((size_t)(b*128+c8+i))*DM + d0];
    #pragma unroll
    for (int i=0;i<8;i++){
      const f32x4 tmp = v[i];
      *(f32x4*)&part[((size_t)(b*128+c8+i))*DM + d0] = run;
      run += tmp;
    }
  }
}

// ---------------- K5: recompute scaled, in-chunk scan + rmsnorm -> yn (CH=32) -------
__global__ __launch_bounds__(256)
void scan_norm(const u16* __restrict__ kb, const u16* __restrict__ vb,
               const u16* __restrict__ rbuf, const float* __restrict__ part,
               const float* __restrict__ decay, const float* __restrict__ lnw,
               u16* __restrict__ yn)
{
  const int c = blockIdx.x & 127, b = blockIdx.x >> 7;
  const int tid = threadIdx.x, lane = tid&63, wave = tid>>6;
  const int d0 = tid*4;
  __shared__ float red[2][4];
  f32x4 run = *(const f32x4*)&part[((size_t)(b*128+c))*DM + d0];
  float ld[4], lw[4];
  #pragma unroll
  for (int j=0;j<4;j++){
    const float dec = 1.f/(1.f+expf(-decay[d0+j]));
    ld[j] = logf(fmaxf(dec, 1e-7f));
    lw[j] = lnw[d0+j];
  }
  for (int t=c*32; t<c*32+32; ++t){
    const size_t base = ((size_t)(b*4096+t))*DM + d0;
    const u16x4 k4 = *(const u16x4*)&kb[base];
    const u16x4 v4 = *(const u16x4*)&vb[base];
    const u16x4 r4 = *(const u16x4*)&rbuf[base];
    const float tf = (float)t;
    float y[4]; float ss = 0.f;
    #pragma unroll
    for (int j=0;j<4;j++){
      const float e = expf(tf*ld[j]);                        // same expr as kv_phase1
      run[j] += bf2f(k4[j])*bf2f(v4[j]) / fmaxf(e, 1e-10f);
      const float st = run[j]*e;                             // unclipped, underflows like ref
      y[j] = bf2f(r4[j])*st;
      ss += y[j]*y[j];
    }
    #pragma unroll
    for (int off=32; off; off>>=1) ss += __shfl_down(ss, off);
    if (lane==0) red[t&1][wave] = ss;
    __builtin_amdgcn_s_barrier();
    const float tot = (red[t&1][0]+red[t&1][1])+(red[t&1][2]+red[t&1][3]);
    const float rs = 1.f/sqrtf(tot*(1.f/1024.f) + 1e-6f);
    u16x4 o;
    #pragma unroll
    for (int j=0;j<4;j++) o[j] = f2bf(y[j]*rs*lw[j]);
    *(u16x4*)&yn[base] = o;
  }
}

extern "C" void kernel_launch(void* const* d_in, const int* in_sizes, int n_in,
                              void* d_out, int out_size, void* d_ws, size_t ws_size,
                              hipStream_t stream)
{
  (void)in_sizes; (void)n_in; (void)out_size; (void)ws_size;
  const float* x    = (const float*)d_in[0];
  const float* Wr   = (const float*)d_in[1];
  const float* Wk   = (const float*)d_in[2];
  const float* Wv   = (const float*)d_in[3];
  const float* Wo   = (const float*)d_in[4];
  const float* dec  = (const float*)d_in[5];
  const float* lnw  = (const float*)d_in[6];

  // layout: wq 8MB | wsc | rbuf 33.5MB | kbuf 33.5MB | vbuf 33.5MB | part 2MB | xb 33.5MB
  //         yn aliases xb (xb dead after GEMM1, yn written by K5, read by GEMM2)
  char* ws = (char*)d_ws;
  u16*   wq     = (u16*)(ws + 0);
  float* wsc    = (float*)(ws + 8388608);
  u16*   rbuf   = (u16*)(ws + 8404992);
  u16*   kbuf   = (u16*)(ws + 41959424);
  u16*   vbuf   = (u16*)(ws + 75513856);
  float* part   = (float*)(ws + 109068288);   // 2MB
  u16*   xb     = (u16*)(ws + 111165440);
  u16*   yn     = xb;

  quantize_w<<<1024, 256, 0, stream>>>(Wr, Wk, Wv, Wo, wq, wsc);
  cvt_x<<<16384, 256, 0, stream>>>(x, xb);
  gemm_p<0><<<dim3(64,12), 512, 0, stream>>>(xb, wq, wsc, rbuf, kbuf, vbuf, nullptr);
  kv_phase1<<<512, 256, 0, stream>>>(kbuf, vbuf, dec, part);
  chunk_prefix<<<4, 256, 0, stream>>>(part);
  scan_norm<<<512, 256, 0, stream>>>(kbuf, vbuf, rbuf, part, dec, lnw, yn);
  gemm_p<1><<<dim3(64,4), 512, 0, stream>>>(yn, wq + 3*1024*1024, wsc + 3072,
                                            nullptr, nullptr, nullptr, (float*)d_out);
}

// Round 6
// 385.857 us; speedup vs baseline: 1.2080x; 1.2080x over previous
//
#include <hip/hip_runtime.h>

typedef unsigned short u16;
typedef __attribute__((ext_vector_type(8))) short bf16x8;
typedef __attribute__((ext_vector_type(4))) float f32x4;
typedef __attribute__((ext_vector_type(4))) unsigned short u16x4;

#define DM 1024

__device__ __forceinline__ float bf2f(u16 u){
  union { unsigned int i; float f; } v; v.i = ((unsigned int)u)<<16; return v.f;
}
__device__ __forceinline__ u16 f2bf(float f){
  unsigned int x = __float_as_uint(f);
  return (u16)((x + 0x7FFFu + ((x>>16)&1u)) >> 16);   // RNE, finite inputs only
}

// ---------------- K0: ternary-quantize the 4 weight matrices ----------------
__global__ __launch_bounds__(256)
void quantize_w(const float* __restrict__ W0, const float* __restrict__ W1,
                const float* __restrict__ W2, const float* __restrict__ W3,
                u16* __restrict__ wq, float* __restrict__ wsc)
{
  const int gr   = blockIdx.x*4 + (threadIdx.x>>6);
  const int lane = threadIdx.x & 63;
  const int mat  = gr >> 10, row = gr & 1023;
  const float* W = (mat==0)?W0:(mat==1)?W1:(mat==2)?W2:W3;
  const float* wr = W + (size_t)row*DM;
  float4 v[4]; float s = 0.f;
  #pragma unroll
  for (int c=0;c<4;c++){
    v[c] = *(const float4*)&wr[c*256 + lane*4];
    s += fabsf(v[c].x)+fabsf(v[c].y)+fabsf(v[c].z)+fabsf(v[c].w);
  }
  #pragma unroll
  for (int off=32; off; off>>=1) s += __shfl_down(s, off);
  s = __shfl(s, 0);
  const float scale = fmaxf(s*(1.f/1024.f), 1e-5f);
  if (lane==0) wsc[gr] = scale;
  u16* wo = wq + (size_t)gr*DM;
  #pragma unroll
  for (int c=0;c<4;c++){
    u16x4 q;
    q[0] = f2bf(fminf(fmaxf(rintf(v[c].x/scale),-1.f),1.f));
    q[1] = f2bf(fminf(fmaxf(rintf(v[c].y/scale),-1.f),1.f));
    q[2] = f2bf(fminf(fmaxf(rintf(v[c].z/scale),-1.f),1.f));
    q[3] = f2bf(fminf(fmaxf(rintf(v[c].w/scale),-1.f),1.f));
    *(u16x4*)&wo[c*256 + lane*4] = q;
  }
}

// ---------------- K1: x f32 -> bf16 ----------------
__global__ void cvt_x(const float* __restrict__ x, u16* __restrict__ xb){
  const int i = (blockIdx.x*256 + threadIdx.x)*4;
  float4 v = *(const float4*)&x[i];
  u16x4 o; o[0]=f2bf(v.x); o[1]=f2bf(v.y); o[2]=f2bf(v.z); o[3]=f2bf(v.w);
  *(u16x4*)&xb[i] = o;
}

// ---------------- K2/K6: 128x128 tile, 4 waves, A in LDS, B global->reg -------------
// out[i,n] = bscale[n] * sum_k A[i,k]*Bq[n,k].  Occupancy-first design:
// LDS 32KB (A dbuf only), B-frags loaded from L2 (wq is 2-6MB, resident).
// Per tile: {Bld(t)x8; Astg(t+1)x4; vmcnt(12)+bar; ds_read x8; vmcnt(4)+lgkm0;
//            32 MFMA; bar}.  FIFO: [Astg(t)4][Bld(t)8][Astg(t+1)4] -> waits 12/4.
// Tail t=15: no stage -> vmcnt(8)/vmcnt(0).  XOR swizzle (row&7)<<4 (R4-proven).

#define SB0 __builtin_amdgcn_sched_barrier(0)
#define BARR do{ SB0; __builtin_amdgcn_s_barrier(); SB0; }while(0)
#define RD(base, off) (*(const bf16x8*)((const char*)(base) + (off)))

#define ASTG(T, BUF) { _Pragma("unroll") \
  for (int q=0;q<4;q++) \
    __builtin_amdgcn_global_load_lds( \
      (const __attribute__((address_space(1))) void*)(asrc[q] + (size_t)(T)*128), \
      (__attribute__((address_space(3))) void*)((char*)(BUF) + ldst + q*4096), 16, 0, 0); }

#define GBODY(T, C, DO_STAGE, WA, WB, TRAIL) { \
  bf16x8 b0[4], b1[4], a0[4], a1[4]; \
  _Pragma("unroll") \
  for (int n=0;n<4;n++){ b0[n]=RD(bptr[n], (size_t)(T)*128); \
                         b1[n]=RD(bptr[n], (size_t)(T)*128+64); } \
  SB0; \
  if (DO_STAGE) ASTG((T)+1, sA[(C)^1]); \
  SB0; \
  asm volatile("s_waitcnt vmcnt(" #WA ")" ::: "memory"); \
  __builtin_amdgcn_s_barrier(); \
  SB0; \
  _Pragma("unroll") \
  for (int m=0;m<4;m++){ a0[m]=RD((const char*)sA[C], arow + m*2048 + koff0); \
                         a1[m]=RD((const char*)sA[C], arow + m*2048 + koff1); } \
  SB0; \
  asm volatile("s_waitcnt vmcnt(" #WB ") lgkmcnt(0)" ::: "memory"); \
  SB0; \
  __builtin_amdgcn_s_setprio(1); \
  _Pragma("unroll") \
  for (int m=0;m<4;m++){ \
    _Pragma("unroll") \
    for (int n=0;n<4;n++){ \
      acc[m][n] = __builtin_amdgcn_mfma_f32_16x16x32_bf16(a0[m], b0[n], acc[m][n], 0,0,0); \
      acc[m][n] = __builtin_amdgcn_mfma_f32_16x16x32_bf16(a1[m], b1[n], acc[m][n], 0,0,0); \
    } } \
  __builtin_amdgcn_s_setprio(0); \
  if (TRAIL) BARR; \
}

template<int MODE>
__global__ __launch_bounds__(256, 3)
void gemm_t(const u16* __restrict__ Ag, const u16* __restrict__ Bg,
            const float* __restrict__ bscale,
            u16* __restrict__ o_r, u16* __restrict__ o_k, u16* __restrict__ o_v,
            float* __restrict__ o_f)
{
  __shared__ u16 sA[2][128*64];                 // 32 KB total
  const int tid = threadIdx.x, wave = tid>>6, lane = tid&63;
  const int lr = lane&15, lg = lane>>4;
  const int wm = wave>>1, wn = wave&1;          // 2M x 2N, per-wave 64x64
  const int bm0 = blockIdx.x*128, bn0 = blockIdx.y*128;
  constexpr int nt = 16;                        // K = 1024 / 64

  // A staging: 4 calls x (256 thr x 16B) = 16KB tile; linear LDS dest, swizzled src
  const int r8   = lane>>3;
  const int scol = ((lane&7)<<4) ^ (r8<<4);
  const char* asrc[4];
  #pragma unroll
  for (int q=0;q<4;q++)
    asrc[q] = (const char*)Ag + (size_t)(bm0 + q*32 + wave*8 + r8)*2048 + scol;
  const int ldst = wave*1024;

  // B-frag global pointers (row = out col, k-contiguous 16B: no transpose needed)
  const char* bptr[4];
  #pragma unroll
  for (int n=0;n<4;n++)
    bptr[n] = (const char*)Bg + (size_t)(bn0 + wn*64 + n*16 + lr)*2048 + lg*16;

  // A ds_read offsets (R4-proven conflict-free geometry)
  const int S = (lr&7)<<4;
  const int koff0 = (lg<<4) ^ S;
  const int koff1 = (64 + (lg<<4)) ^ S;
  const int arow = (wm*64 + lr)*128;            // + m*2048

  f32x4 acc[4][4];
  #pragma unroll
  for (int i=0;i<4;i++)
    #pragma unroll
    for (int j=0;j<4;j++) acc[i][j] = (f32x4){0.f,0.f,0.f,0.f};

  ASTG(0, sA[0]);                               // prologue: A(0) in flight (4)

  for (int t=0; t<nt-1; ++t){
    const int c = t&1;
    GBODY(t, c, true, 12, 4, true)
  }
  GBODY(nt-1, (nt-1)&1, false, 8, 0, false)     // tail: no stage, drain B fully

  // ---- epilogue: C/D col=lane&15, row=(lane>>4)*4+reg ----
  #pragma unroll
  for (int mi=0; mi<4; ++mi){
    #pragma unroll
    for (int ni=0; ni<4; ++ni){
      const int col = bn0 + wn*64 + ni*16 + lr;
      const float sc = bscale[col];
      const int rowb = bm0 + wm*64 + mi*16 + lg*4;
      const f32x4 a = acc[mi][ni];
      if (MODE==0){
        const int seg = col>>10, d = col&1023;  // uniform per block (1024%128==0)
        #pragma unroll
        for (int r2=0;r2<4;r2++){
          const size_t o = (size_t)(rowb+r2)*DM + d;
          const float val = a[r2]*sc;
          if (seg==0)      o_r[o] = f2bf(1.f/(1.f+expf(-val)));
          else if (seg==1) o_k[o] = f2bf(val);
          else             o_v[o] = f2bf(val);
        }
      } else {
        #pragma unroll
        for (int r2=0;r2<4;r2++)
          o_f[(size_t)(rowb+r2)*DM + col] = a[r2]*sc;
      }
    }
  }
}

// ---------------- K3: per-chunk sums of k*v / max(exp(t*ld),1e-10), CH=32 ----------
__global__ __launch_bounds__(256)
void kv_phase1(const u16* __restrict__ kb, const u16* __restrict__ vb,
               const float* __restrict__ decay, float* __restrict__ part)
{
  const int c = blockIdx.x & 127, b = blockIdx.x >> 7;
  const int d0 = threadIdx.x*4;
  float ld[4]; f32x4 sum = {0.f,0.f,0.f,0.f};
  #pragma unroll
  for (int j=0;j<4;j++){
    const float dec = 1.f/(1.f+expf(-decay[d0+j]));
    ld[j] = logf(fmaxf(dec, 1e-7f));
  }
  for (int t=c*32; t<c*32+32; ++t){
    const size_t base = ((size_t)(b*4096 + t))*DM + d0;
    const u16x4 k4 = *(const u16x4*)&kb[base];
    const u16x4 v4 = *(const u16x4*)&vb[base];
    const float tf = (float)t;
    #pragma unroll
    for (int j=0;j<4;j++){
      const float e = expf(tf*ld[j]);                        // underflows to 0 like ref
      sum[j] += bf2f(k4[j])*bf2f(v4[j]) / fmaxf(e, 1e-10f);
    }
  }
  *(f32x4*)&part[((size_t)(b*128+c))*DM + d0] = sum;
}

// ---------------- K4: exclusive prefix over 128 chunk sums (8-wide pipelined) -------
__global__ void chunk_prefix(float* __restrict__ part){
  const int g = blockIdx.x*256 + threadIdx.x;  // 0..1023
  const int b = g >> 8, d0 = (g & 255)*4;
  f32x4 run = {0.f,0.f,0.f,0.f};
  for (int c8=0; c8<128; c8+=8){
    f32x4 v[8];
    #pragma unroll
    for (int i=0;i<8;i++)
      v[i] = *(const f32x4*)&part[((size_t)(b*128+c8+i))*DM + d0];
    #pragma unroll
    for (int i=0;i<8;i++){
      const f32x4 tmp = v[i];
      *(f32x4*)&part[((size_t)(b*128+c8+i))*DM + d0] = run;
      run += tmp;
    }
  }
}

// ---------------- K5: recompute scaled, in-chunk scan + rmsnorm -> yn (CH=32) -------
__global__ __launch_bounds__(256)
void scan_norm(const u16* __restrict__ kb, const u16* __restrict__ vb,
               const u16* __restrict__ rbuf, const float* __restrict__ part,
               const float* __restrict__ decay, const float* __restrict__ lnw,
               u16* __restrict__ yn)
{
  const int c = blockIdx.x & 127, b = blockIdx.x >> 7;
  const int tid = threadIdx.x, lane = tid&63, wave = tid>>6;
  const int d0 = tid*4;
  __shared__ float red[2][4];
  f32x4 run = *(const f32x4*)&part[((size_t)(b*128+c))*DM + d0];
  float ld[4], lw[4];
  #pragma unroll
  for (int j=0;j<4;j++){
    const float dec = 1.f/(1.f+expf(-decay[d0+j]));
    ld[j] = logf(fmaxf(dec, 1e-7f));
    lw[j] = lnw[d0+j];
  }
  for (int t=c*32; t<c*32+32; ++t){
    const size_t base = ((size_t)(b*4096+t))*DM + d0;
    const u16x4 k4 = *(const u16x4*)&kb[base];
    const u16x4 v4 = *(const u16x4*)&vb[base];
    const u16x4 r4 = *(const u16x4*)&rbuf[base];
    const float tf = (float)t;
    float y[4]; float ss = 0.f;
    #pragma unroll
    for (int j=0;j<4;j++){
      const float e = expf(tf*ld[j]);                        // same expr as kv_phase1
      run[j] += bf2f(k4[j])*bf2f(v4[j]) / fmaxf(e, 1e-10f);
      const float st = run[j]*e;                             // unclipped, underflows like ref
      y[j] = bf2f(r4[j])*st;
      ss += y[j]*y[j];
    }
    #pragma unroll
    for (int off=32; off; off>>=1) ss += __shfl_down(ss, off);
    if (lane==0) red[t&1][wave] = ss;
    __builtin_amdgcn_s_barrier();
    const float tot = (red[t&1][0]+red[t&1][1])+(red[t&1][2]+red[t&1][3]);
    const float rs = 1.f/sqrtf(tot*(1.f/1024.f) + 1e-6f);
    u16x4 o;
    #pragma unroll
    for (int j=0;j<4;j++) o[j] = f2bf(y[j]*rs*lw[j]);
    *(u16x4*)&yn[base] = o;
  }
}

extern "C" void kernel_launch(void* const* d_in, const int* in_sizes, int n_in,
                              void* d_out, int out_size, void* d_ws, size_t ws_size,
                              hipStream_t stream)
{
  (void)in_sizes; (void)n_in; (void)out_size; (void)ws_size;
  const float* x    = (const float*)d_in[0];
  const float* Wr   = (const float*)d_in[1];
  const float* Wk   = (const float*)d_in[2];
  const float* Wv   = (const float*)d_in[3];
  const float* Wo   = (const float*)d_in[4];
  const float* dec  = (const float*)d_in[5];
  const float* lnw  = (const float*)d_in[6];

  // layout: wq 8MB | wsc | rbuf 33.5MB | kbuf 33.5MB | vbuf 33.5MB | part 2MB | xb 33.5MB
  //         yn aliases xb (xb dead after GEMM1, yn written by K5, read by GEMM2)
  char* ws = (char*)d_ws;
  u16*   wq     = (u16*)(ws + 0);
  float* wsc    = (float*)(ws + 8388608);
  u16*   rbuf   = (u16*)(ws + 8404992);
  u16*   kbuf   = (u16*)(ws + 41959424);
  u16*   vbuf   = (u16*)(ws + 75513856);
  float* part   = (float*)(ws + 109068288);   // 2MB
  u16*   xb     = (u16*)(ws + 111165440);
  u16*   yn     = xb;

  quantize_w<<<1024, 256, 0, stream>>>(Wr, Wk, Wv, Wo, wq, wsc);
  cvt_x<<<16384, 256, 0, stream>>>(x, xb);
  gemm_t<0><<<dim3(128,24), 256, 0, stream>>>(xb, wq, wsc, rbuf, kbuf, vbuf, nullptr);
  kv_phase1<<<512, 256, 0, stream>>>(kbuf, vbuf, dec, part);
  chunk_prefix<<<4, 256, 0, stream>>>(part);
  scan_norm<<<512, 256, 0, stream>>>(kbuf, vbuf, rbuf, part, dec, lnw, yn);
  gemm_t<1><<<dim3(128,8), 256, 0, stream>>>(yn, wq + 3*1024*1024, wsc + 3072,
                                             nullptr, nullptr, nullptr, (float*)d_out);
}

// Round 7
// 243.973 us; speedup vs baseline: 1.9106x; 1.5816x over previous
//
#include <hip/hip_runtime.h>

typedef unsigned short u16;
typedef __attribute__((ext_vector_type(8))) short bf16x8;
typedef __attribute__((ext_vector_type(4))) float f32x4;
typedef __attribute__((ext_vector_type(4))) unsigned short u16x4;

#define DM 1024

__device__ __forceinline__ float bf2f(u16 u){
  union { unsigned int i; float f; } v; v.i = ((unsigned int)u)<<16; return v.f;
}
__device__ __forceinline__ u16 f2bf(float f){
  unsigned int x = __float_as_uint(f);
  return (u16)((x + 0x7FFFu + ((x>>16)&1u)) >> 16);   // RNE, finite inputs only
}

// ---------------- K0: ternary-quantize; K/V rows interleaved ----------------
// wq rows: [0,1024) = R ; [1024,3072) = K[d],V[d] interleaved (row 1024+2d = Wk[d],
// 1024+2d+1 = Wv[d]) ; [3072,4096) = O.  wsc matches row order.
__global__ __launch_bounds__(256)
void quantize_w(const float* __restrict__ W0, const float* __restrict__ W1,
                const float* __restrict__ W2, const float* __restrict__ W3,
                u16* __restrict__ wq, float* __restrict__ wsc)
{
  const int gr   = blockIdx.x*4 + (threadIdx.x>>6);  // output row 0..4095 (wave-uniform)
  const int lane = threadIdx.x & 63;
  const float* W; int row;
  if (gr < 1024)      { W = W0; row = gr; }
  else if (gr < 3072) { row = (gr-1024)>>1; W = (gr&1) ? W2 : W1; }
  else                { W = W3; row = gr-3072; }
  const float* wr = W + (size_t)row*DM;
  float4 v[4]; float s = 0.f;
  #pragma unroll
  for (int c=0;c<4;c++){
    v[c] = *(const float4*)&wr[c*256 + lane*4];
    s += fabsf(v[c].x)+fabsf(v[c].y)+fabsf(v[c].z)+fabsf(v[c].w);
  }
  #pragma unroll
  for (int off=32; off; off>>=1) s += __shfl_down(s, off);
  s = __shfl(s, 0);
  const float scale = fmaxf(s*(1.f/1024.f), 1e-5f);
  if (lane==0) wsc[gr] = scale;
  u16* wo = wq + (size_t)gr*DM;
  #pragma unroll
  for (int c=0;c<4;c++){
    u16x4 q;
    q[0] = f2bf(fminf(fmaxf(rintf(v[c].x/scale),-1.f),1.f));
    q[1] = f2bf(fminf(fmaxf(rintf(v[c].y/scale),-1.f),1.f));
    q[2] = f2bf(fminf(fmaxf(rintf(v[c].z/scale),-1.f),1.f));
    q[3] = f2bf(fminf(fmaxf(rintf(v[c].w/scale),-1.f),1.f));
    *(u16x4*)&wo[c*256 + lane*4] = q;
  }
}

// ---------------- K1: x f32 -> bf16 ----------------
__global__ void cvt_x(const float* __restrict__ x, u16* __restrict__ xb){
  const int i = (blockIdx.x*256 + threadIdx.x)*4;
  float4 v = *(const float4*)&x[i];
  u16x4 o; o[0]=f2bf(v.x); o[1]=f2bf(v.y); o[2]=f2bf(v.z); o[3]=f2bf(v.w);
  *(u16x4*)&xb[i] = o;
}

// ---------------- K2/K6: 256x256 GEMM, BK=64, read-pipelined 4-phase (R4-proven) ----
// MODE 0: N=3072; y<4 -> sigmoid -> r ; y>=4 (interleaved k/v cols) -> epilogue forms
//         kv = k*v via __shfl_xor(val,1) and even-lr lanes write kvbuf (d = (col-1024)>>1).
// MODE 1: N=1024, f32 out.

#define SB0 __builtin_amdgcn_sched_barrier(0)
#define WL4  do{ asm volatile("s_waitcnt lgkmcnt(4)" ::: "memory"); SB0; }while(0)
#define WL12 do{ asm volatile("s_waitcnt lgkmcnt(12)" ::: "memory"); SB0; }while(0)
#define WL0  do{ asm volatile("s_waitcnt lgkmcnt(0)" ::: "memory"); SB0; }while(0)
#define VM4  do{ asm volatile("s_waitcnt vmcnt(4)" ::: "memory"); SB0; }while(0)
#define VM0  do{ asm volatile("s_waitcnt vmcnt(0)" ::: "memory"); SB0; }while(0)
#define BARR do{ SB0; __builtin_amdgcn_s_barrier(); SB0; }while(0)

#define STG(gB, off, T, Q, buf) \
  __builtin_amdgcn_global_load_lds( \
    (const __attribute__((address_space(1))) void*)((const char*)(gB) + (off) + (Q)*131072 + (size_t)(T)*128), \
    (__attribute__((address_space(3))) void*)((char*)(buf) + ldst + (Q)*8192), 16, 0, 0)

#define RD(base, off) (*(const bf16x8*)((const char*)(base) + (off)))

#define MFMA16(AF, B, MI) \
  __builtin_amdgcn_s_setprio(1); \
  _Pragma("unroll") \
  for (int ni=0; ni<4; ++ni){ \
    acc[MI][ni]   = __builtin_amdgcn_mfma_f32_16x16x32_bf16(AF[0], B[ni],   acc[MI][ni],   0,0,0); \
    acc[MI][ni]   = __builtin_amdgcn_mfma_f32_16x16x32_bf16(AF[1], B[4+ni], acc[MI][ni],   0,0,0); \
    acc[MI+1][ni] = __builtin_amdgcn_mfma_f32_16x16x32_bf16(AF[2], B[ni],   acc[MI+1][ni], 0,0,0); \
    acc[MI+1][ni] = __builtin_amdgcn_mfma_f32_16x16x32_bf16(AF[3], B[4+ni], acc[MI+1][ni], 0,0,0); \
  } \
  __builtin_amdgcn_s_setprio(0)

#define TILE(T, C, BCUR, BNXT) { \
  const char* la  = (const char*)sA[C]; \
  const char* lnA = (const char*)sA[(C)^1]; \
  const char* lnB = (const char*)sB[(C)^1]; \
  /* P0: read ay=mi2,3 ; stage A(T+1) */ \
  ay[0]=RD(la, arow+2*2048+koff0); ay[1]=RD(la, arow+2*2048+koff1); \
  ay[2]=RD(la, arow+3*2048+koff0); ay[3]=RD(la, arow+3*2048+koff1); \
  if ((T)+1<nt){ STG(Ag, aoff, (T)+1, 0, sA[(C)^1]); STG(Ag, aoff, (T)+1, 1, sA[(C)^1]); \
                 STG(Ag, aoff, (T)+1, 2, sA[(C)^1]); STG(Ag, aoff, (T)+1, 3, sA[(C)^1]); } \
  WL4; MFMA16(ax, BCUR, 0); BARR; \
  /* P1: read ax=mi4,5 ; stage B(T+2) q0,q1 */ \
  ax[0]=RD(la, arow+4*2048+koff0); ax[1]=RD(la, arow+4*2048+koff1); \
  ax[2]=RD(la, arow+5*2048+koff0); ax[3]=RD(la, arow+5*2048+koff1); \
  if ((T)+2<nt){ STG(Bg, boff, (T)+2, 0, sB[C]); STG(Bg, boff, (T)+2, 1, sB[C]); } \
  WL4; MFMA16(ay, BCUR, 2); BARR; \
  /* P2: read ay=mi6,7 ; stage B(T+2) q2,q3 ; per-tile vmcnt BEFORE barrier */ \
  ay[0]=RD(la, arow+6*2048+koff0); ay[1]=RD(la, arow+6*2048+koff1); \
  ay[2]=RD(la, arow+7*2048+koff0); ay[3]=RD(la, arow+7*2048+koff1); \
  if ((T)+2<nt){ STG(Bg, boff, (T)+2, 2, sB[C]); STG(Bg, boff, (T)+2, 3, sB[C]); } \
  WL4; MFMA16(ax, BCUR, 4); SB0; \
  if ((T)==nt-2) { VM0; } else if ((T)<nt-2) { VM4; } \
  BARR; \
  /* P3: prefetch next tile's B (8) + A mi0,1 (4) ; counted wait ; MFMA mi6,7 */ \
  if ((T)<nt-1){ \
    BNXT[0]=RD(lnB, brow+0*2048+koff0); BNXT[1]=RD(lnB, brow+1*2048+koff0); \
    BNXT[2]=RD(lnB, brow+2*2048+koff0); BNXT[3]=RD(lnB, brow+3*2048+koff0); \
    BNXT[4]=RD(lnB, brow+0*2048+koff1); BNXT[5]=RD(lnB, brow+1*2048+koff1); \
    BNXT[6]=RD(lnB, brow+2*2048+koff1); BNXT[7]=RD(lnB, brow+3*2048+koff1); \
    ax[0]=RD(lnA, arow+0*2048+koff0); ax[1]=RD(lnA, arow+0*2048+koff1); \
    ax[2]=RD(lnA, arow+1*2048+koff0); ax[3]=RD(lnA, arow+1*2048+koff1); \
    WL12; \
  } else { WL0; } \
  MFMA16(ay, BCUR, 6); BARR; \
}

template<int MODE>
__global__ __launch_bounds__(512, 2)
void gemm_p(const u16* __restrict__ Ag, const u16* __restrict__ Bg,
            const float* __restrict__ bscale,
            u16* __restrict__ o_r, u16* __restrict__ o_kv,
            float* __restrict__ o_f)
{
  __shared__ u16 sA[2][256*64];
  __shared__ u16 sB[2][256*64];
  const int tid = threadIdx.x, wave = tid>>6, lane = tid&63;
  const int lr = lane&15, lg = lane>>4;
  const int wm = wave>>2, wn = wave&3;
  const int bm0 = blockIdx.x*256, bn0 = blockIdx.y*256;
  constexpr int nt = 16;                        // K = 1024 / 64

  const int r8   = lane>>3;
  const int scol = ((lane&7)<<4) ^ (r8<<4);     // pre-swizzled source col (bytes)
  const size_t aoff = (size_t)(bm0 + wave*8 + r8)*2048 + scol;
  const size_t boff = (size_t)(bn0 + wave*8 + r8)*2048 + scol;
  const int ldst = wave*1024;
  const int S = (lr&7)<<4;
  const int koff0 = (0  + (lg<<4)) ^ S;
  const int koff1 = (64 + (lg<<4)) ^ S;
  const int arow = (wm*128 + lr)*128;
  const int brow = (wn*64  + lr)*128;

  f32x4 acc[8][4];
  #pragma unroll
  for (int i=0;i<8;i++)
    #pragma unroll
    for (int j=0;j<4;j++) acc[i][j] = (f32x4){0.f,0.f,0.f,0.f};

  bf16x8 bc[8], bn2[8], ax[4], ay[4];

  #pragma unroll
  for (int q=0;q<4;q++){ STG(Ag, aoff, 0, q, sA[0]); STG(Bg, boff, 0, q, sB[0]); }
  #pragma unroll
  for (int q=0;q<4;q++){ STG(Bg, boff, 1, q, sB[1]); }
  VM4;
  BARR;
  {
    const char* la0 = (const char*)sA[0];
    const char* lb0 = (const char*)sB[0];
    bc[0]=RD(lb0, brow+0*2048+koff0); bc[1]=RD(lb0, brow+1*2048+koff0);
    bc[2]=RD(lb0, brow+2*2048+koff0); bc[3]=RD(lb0, brow+3*2048+koff0);
    bc[4]=RD(lb0, brow+0*2048+koff1); bc[5]=RD(lb0, brow+1*2048+koff1);
    bc[6]=RD(lb0, brow+2*2048+koff1); bc[7]=RD(lb0, brow+3*2048+koff1);
    ax[0]=RD(la0, arow+0*2048+koff0); ax[1]=RD(la0, arow+0*2048+koff1);
    ax[2]=RD(la0, arow+1*2048+koff0); ax[3]=RD(la0, arow+1*2048+koff1);
  }
  for (int tp=0; tp<nt; tp+=2){
    TILE(tp,   0, bc, bn2)
    TILE(tp+1, 1, bn2, bc)
  }

  // ---- epilogue: C/D col=lane&15, row=(lane>>4)*4+reg ----
  #pragma unroll
  for (int mi=0; mi<8; ++mi){
    #pragma unroll
    for (int ni=0; ni<4; ++ni){
      const int col = bn0 + wn*64 + ni*16 + lr;
      const float sc = bscale[col];
      const int rowb = bm0 + wm*128 + mi*16 + lg*4;
      const f32x4 a = acc[mi][ni];
      if (MODE==0){
        if (bn0 < 1024){                        // r segment (block-uniform)
          #pragma unroll
          for (int r2=0;r2<4;r2++){
            const float val = a[r2]*sc;
            o_r[(size_t)(rowb+r2)*DM + col] = f2bf(1.f/(1.f+expf(-val)));
          }
        } else {                                // interleaved k/v: form product in-lane-pair
          const int dv = (col - 1024) >> 1;     // even-lr lanes: d index
          #pragma unroll
          for (int r2=0;r2<4;r2++){
            const float val = a[r2]*sc;         // k*sck (even lr) or v*scv (odd lr)
            const float pr  = val * __shfl_xor(val, 1);
            if (!(lr & 1))
              o_kv[(size_t)(rowb+r2)*DM + dv] = f2bf(pr);
          }
        }
      } else {
        #pragma unroll
        for (int r2=0;r2<4;r2++)
          o_f[(size_t)(rowb+r2)*DM + col] = a[r2]*sc;
      }
    }
  }
}

// ---------------- K3: per-chunk sums of kv / max(exp(t*ld),1e-10), CH=32 -----------
__global__ __launch_bounds__(256)
void kv_phase1(const u16* __restrict__ kv, const float* __restrict__ decay,
               float* __restrict__ part)
{
  const int c = blockIdx.x & 127, b = blockIdx.x >> 7;
  const int d0 = threadIdx.x*4;
  float ld[4]; f32x4 sum = {0.f,0.f,0.f,0.f};
  #pragma unroll
  for (int j=0;j<4;j++){
    const float dec = 1.f/(1.f+expf(-decay[d0+j]));
    ld[j] = logf(fmaxf(dec, 1e-7f));
  }
  for (int t=c*32; t<c*32+32; ++t){
    const size_t base = ((size_t)(b*4096 + t))*DM + d0;
    const u16x4 p4 = *(const u16x4*)&kv[base];
    const float tf = (float)t;
    #pragma unroll
    for (int j=0;j<4;j++){
      const float e = expf(tf*ld[j]);                        // underflows to 0 like ref
      sum[j] += bf2f(p4[j]) / fmaxf(e, 1e-10f);
    }
  }
  *(f32x4*)&part[((size_t)(b*128+c))*DM + d0] = sum;
}

// ---------------- K4: exclusive prefix over 128 chunk sums (8-wide pipelined) -------
__global__ void chunk_prefix(float* __restrict__ part){
  const int g = blockIdx.x*256 + threadIdx.x;  // 0..1023
  const int b = g >> 8, d0 = (g & 255)*4;
  f32x4 run = {0.f,0.f,0.f,0.f};
  for (int c8=0; c8<128; c8+=8){
    f32x4 v[8];
    #pragma unroll
    for (int i=0;i<8;i++)
      v[i] = *(const f32x4*)&part[((size_t)(b*128+c8+i))*DM + d0];
    #pragma unroll
    for (int i=0;i<8;i++){
      const f32x4 tmp = v[i];
      *(f32x4*)&part[((size_t)(b*128+c8+i))*DM + d0] = run;
      run += tmp;
    }
  }
}

// ---------------- K5: in-chunk scan + y=r*state + rmsnorm -> yn (CH=32) -------------
__global__ __launch_bounds__(256)
void scan_norm(const u16* __restrict__ kv, const u16* __restrict__ rbuf,
               const float* __restrict__ part, const float* __restrict__ decay,
               const float* __restrict__ lnw, u16* __restrict__ yn)
{
  const int c = blockIdx.x & 127, b = blockIdx.x >> 7;
  const int tid = threadIdx.x, lane = tid&63, wave = tid>>6;
  const int d0 = tid*4;
  __shared__ float red[2][4];
  f32x4 run = *(const f32x4*)&part[((size_t)(b*128+c))*DM + d0];
  float ld[4], lw[4];
  #pragma unroll
  for (int j=0;j<4;j++){
    const float dec = 1.f/(1.f+expf(-decay[d0+j]));
    ld[j] = logf(fmaxf(dec, 1e-7f));
    lw[j] = lnw[d0+j];
  }
  for (int t=c*32; t<c*32+32; ++t){
    const size_t base = ((size_t)(b*4096+t))*DM + d0;
    const u16x4 p4 = *(const u16x4*)&kv[base];
    const u16x4 r4 = *(const u16x4*)&rbuf[base];
    const float tf = (float)t;
    float y[4]; float ss = 0.f;
    #pragma unroll
    for (int j=0;j<4;j++){
      const float e = expf(tf*ld[j]);                        // same expr as kv_phase1
      run[j] += bf2f(p4[j]) / fmaxf(e, 1e-10f);
      const float st = run[j]*e;                             // unclipped, underflows like ref
      y[j] = bf2f(r4[j])*st;
      ss += y[j]*y[j];
    }
    #pragma unroll
    for (int off=32; off; off>>=1) ss += __shfl_down(ss, off);
    if (lane==0) red[t&1][wave] = ss;
    __builtin_amdgcn_s_barrier();
    const float tot = (red[t&1][0]+red[t&1][1])+(red[t&1][2]+red[t&1][3]);
    const float rs = 1.f/sqrtf(tot*(1.f/1024.f) + 1e-6f);
    u16x4 o;
    #pragma unroll
    for (int j=0;j<4;j++) o[j] = f2bf(y[j]*rs*lw[j]);
    *(u16x4*)&yn[base] = o;
  }
}

extern "C" void kernel_launch(void* const* d_in, const int* in_sizes, int n_in,
                              void* d_out, int out_size, void* d_ws, size_t ws_size,
                              hipStream_t stream)
{
  (void)in_sizes; (void)n_in; (void)out_size; (void)ws_size;
  const float* x    = (const float*)d_in[0];
  const float* Wr   = (const float*)d_in[1];
  const float* Wk   = (const float*)d_in[2];
  const float* Wv   = (const float*)d_in[3];
  const float* Wo   = (const float*)d_in[4];
  const float* dec  = (const float*)d_in[5];
  const float* lnw  = (const float*)d_in[6];

  // layout: wq 8MB | wsc | rbuf 33.5MB | kvbuf 33.5MB | part 2MB | xb 33.5MB | yn 33.5MB
  char* ws = (char*)d_ws;
  u16*   wq     = (u16*)(ws + 0);
  float* wsc    = (float*)(ws + 8388608);
  u16*   rbuf   = (u16*)(ws + 8404992);
  u16*   kvbuf  = (u16*)(ws + 41959424);
  float* part   = (float*)(ws + 75513856);    // 2MB
  u16*   xb     = (u16*)(ws + 77611008);
  u16*   yn     = (u16*)(ws + 111165440);     // ends 144,719,872

  quantize_w<<<1024, 256, 0, stream>>>(Wr, Wk, Wv, Wo, wq, wsc);
  cvt_x<<<16384, 256, 0, stream>>>(x, xb);
  gemm_p<0><<<dim3(64,12), 512, 0, stream>>>(xb, wq, wsc, rbuf, kvbuf, nullptr);
  kv_phase1<<<512, 256, 0, stream>>>(kvbuf, dec, part);
  chunk_prefix<<<4, 256, 0, stream>>>(part);
  scan_norm<<<512, 256, 0, stream>>>(kvbuf, rbuf, part, dec, lnw, yn);
  gemm_p<1><<<dim3(64,4), 512, 0, stream>>>(yn, wq + 3*1024*1024, wsc + 3072,
                                            nullptr, nullptr, (float*)d_out);
}

// Round 8
// 242.183 us; speedup vs baseline: 1.9247x; 1.0074x over previous
//
#include <hip/hip_runtime.h>

typedef unsigned short u16;
typedef __attribute__((ext_vector_type(8))) short bf16x8;
typedef __attribute__((ext_vector_type(4))) float f32x4;
typedef __attribute__((ext_vector_type(4))) unsigned short u16x4;

#define DM 1024

__device__ __forceinline__ float bf2f(u16 u){
  union { unsigned int i; float f; } v; v.i = ((unsigned int)u)<<16; return v.f;
}
__device__ __forceinline__ u16 f2bf(float f){
  unsigned int x = __float_as_uint(f);
  return (u16)((x + 0x7FFFu + ((x>>16)&1u)) >> 16);   // RNE, finite inputs only
}

// ---------------- K0: ternary-quantize; K/V rows interleaved ----------------
// wq rows: [0,1024) = R ; [1024,3072) = K[d],V[d] interleaved ; [3072,4096) = O.
__global__ __launch_bounds__(256)
void quantize_w(const float* __restrict__ W0, const float* __restrict__ W1,
                const float* __restrict__ W2, const float* __restrict__ W3,
                u16* __restrict__ wq, float* __restrict__ wsc)
{
  const int gr   = blockIdx.x*4 + (threadIdx.x>>6);  // output row 0..4095 (wave-uniform)
  const int lane = threadIdx.x & 63;
  const float* W; int row;
  if (gr < 1024)      { W = W0; row = gr; }
  else if (gr < 3072) { row = (gr-1024)>>1; W = (gr&1) ? W2 : W1; }
  else                { W = W3; row = gr-3072; }
  const float* wr = W + (size_t)row*DM;
  float4 v[4]; float s = 0.f;
  #pragma unroll
  for (int c=0;c<4;c++){
    v[c] = *(const float4*)&wr[c*256 + lane*4];
    s += fabsf(v[c].x)+fabsf(v[c].y)+fabsf(v[c].z)+fabsf(v[c].w);
  }
  #pragma unroll
  for (int off=32; off; off>>=1) s += __shfl_down(s, off);
  s = __shfl(s, 0);
  const float scale = fmaxf(s*(1.f/1024.f), 1e-5f);
  if (lane==0) wsc[gr] = scale;
  u16* wo = wq + (size_t)gr*DM;
  #pragma unroll
  for (int c=0;c<4;c++){
    u16x4 q;
    q[0] = f2bf(fminf(fmaxf(rintf(v[c].x/scale),-1.f),1.f));
    q[1] = f2bf(fminf(fmaxf(rintf(v[c].y/scale),-1.f),1.f));
    q[2] = f2bf(fminf(fmaxf(rintf(v[c].z/scale),-1.f),1.f));
    q[3] = f2bf(fminf(fmaxf(rintf(v[c].w/scale),-1.f),1.f));
    *(u16x4*)&wo[c*256 + lane*4] = q;
  }
}

// ---------------- K1: x f32 -> bf16 ----------------
__global__ void cvt_x(const float* __restrict__ x, u16* __restrict__ xb){
  const int i = (blockIdx.x*256 + threadIdx.x)*4;
  float4 v = *(const float4*)&x[i];
  u16x4 o; o[0]=f2bf(v.x); o[1]=f2bf(v.y); o[2]=f2bf(v.z); o[3]=f2bf(v.w);
  *(u16x4*)&xb[i] = o;
}

// ---------------- K2/K6: m97-style 128x128 single-buffer GEMM, 4 blocks/CU ----------
// out[i,n] = bscale[n] * sum_k A[i,k]*Bq[n,k].
// Occupancy-first (m97/m114): 32KB LDS single-buffer, 256 thr (2x2 waves, 64x64 each),
// plain {stage t; syncthreads; compute t; syncthreads} loop — cross-BLOCK TLP
// (4 blocks/CU) hides the barrier drains; compiler schedules lgkmcnt fine-grained.
// XOR swizzle (row&7)<<4 on stage source + ds_read (involution, R4-proven).
// MODE 0: N=3072; cols<1024 -> sigmoid -> r ; cols>=1024 interleaved k/v -> kv product.
// MODE 1: N=1024, f32 out.

#define RD(base, off) (*(const bf16x8*)((const char*)(base) + (off)))

template<int MODE>
__global__ __launch_bounds__(256, 4)
void gemm_s(const u16* __restrict__ Ag, const u16* __restrict__ Bq,
            const float* __restrict__ bscale,
            u16* __restrict__ o_r, u16* __restrict__ o_kv,
            float* __restrict__ o_f)
{
  __shared__ u16 sA[128*64];                    // 16KB
  __shared__ u16 sB[128*64];                    // 16KB
  const int tid = threadIdx.x, wave = tid>>6, lane = tid&63;
  const int lr = lane&15, lg = lane>>4;
  const int wm = wave>>1, wn = wave&1;          // 2M x 2N, per-wave 64x64
  const int bm0 = blockIdx.x*128, bn0 = blockIdx.y*128;
  constexpr int nt = 16;                        // K = 1024 / 64

  // staging: 4 gload_lds per matrix per tile; 256 thr x 16B each; linear LDS dest,
  // pre-swizzled global source column (involution with the ds_read XOR).
  const int r8   = lane>>3;
  const int scol = ((lane&7)<<4) ^ (r8<<4);
  const size_t aoff = (size_t)(bm0 + wave*8 + r8)*2048 + scol;
  const size_t boff = (size_t)(bn0 + wave*8 + r8)*2048 + scol;
  const int ldst = wave*1024;                   // + q*4096 (32 rows per q-chunk)

  // ds_read offsets: row = (w*64 + frag*16 + lr), swizzle key = (lr&7) (row&7 == lr&7)
  const int S = (lr&7)<<4;
  const int koff0 = ((lg<<4)     ) ^ S;
  const int koff1 = (64 + (lg<<4)) ^ S;
  const int arow = (wm*64 + lr)*128;            // + mi*2048
  const int brow = (wn*64 + lr)*128;            // + ni*2048

  f32x4 acc[4][4];
  #pragma unroll
  for (int i=0;i<4;i++)
    #pragma unroll
    for (int j=0;j<4;j++) acc[i][j] = (f32x4){0.f,0.f,0.f,0.f};

  for (int t=0; t<nt; ++t){
    // ---- stage tile t (A 16KB + B 16KB) ----
    #pragma unroll
    for (int q=0;q<4;q++){
      __builtin_amdgcn_global_load_lds(
        (const __attribute__((address_space(1))) void*)((const char*)Ag + aoff + q*65536 + (size_t)t*128),
        (__attribute__((address_space(3))) void*)((char*)sA + ldst + q*4096), 16, 0, 0);
      __builtin_amdgcn_global_load_lds(
        (const __attribute__((address_space(1))) void*)((const char*)Bq + boff + q*65536 + (size_t)t*128),
        (__attribute__((address_space(3))) void*)((char*)sB + ldst + q*4096), 16, 0, 0);
    }
    __syncthreads();                            // stages landed (drain)
    // ---- compute tile t: ks0 then ks1, compiler-scheduled ----
    {
      bf16x8 a[4], b[4];
      #pragma unroll
      for (int m=0;m<4;m++) a[m] = RD(sA, arow + m*2048 + koff0);
      #pragma unroll
      for (int n=0;n<4;n++) b[n] = RD(sB, brow + n*2048 + koff0);
      #pragma unroll
      for (int m=0;m<4;m++)
        #pragma unroll
        for (int n=0;n<4;n++)
          acc[m][n] = __builtin_amdgcn_mfma_f32_16x16x32_bf16(a[m], b[n], acc[m][n], 0,0,0);
      #pragma unroll
      for (int m=0;m<4;m++) a[m] = RD(sA, arow + m*2048 + koff1);
      #pragma unroll
      for (int n=0;n<4;n++) b[n] = RD(sB, brow + n*2048 + koff1);
      #pragma unroll
      for (int m=0;m<4;m++)
        #pragma unroll
        for (int n=0;n<4;n++)
          acc[m][n] = __builtin_amdgcn_mfma_f32_16x16x32_bf16(a[m], b[n], acc[m][n], 0,0,0);
    }
    __syncthreads();                            // reads done before next overwrite
  }

  // ---- epilogue: C/D col=lane&15, row=(lane>>4)*4+reg ----
  #pragma unroll
  for (int mi=0; mi<4; ++mi){
    #pragma unroll
    for (int ni=0; ni<4; ++ni){
      const int col = bn0 + wn*64 + ni*16 + lr;
      const float sc = bscale[col];
      const int rowb = bm0 + wm*64 + mi*16 + lg*4;
      const f32x4 a = acc[mi][ni];
      if (MODE==0){
        if (bn0 < 1024){                        // r segment (block-uniform)
          #pragma unroll
          for (int r2=0;r2<4;r2++){
            const float val = a[r2]*sc;
            o_r[(size_t)(rowb+r2)*DM + col] = f2bf(1.f/(1.f+expf(-val)));
          }
        } else {                                // interleaved k/v: product in lane-pair
          const int dv = (col - 1024) >> 1;
          #pragma unroll
          for (int r2=0;r2<4;r2++){
            const float val = a[r2]*sc;
            const float pr  = val * __shfl_xor(val, 1);
            if (!(lr & 1))
              o_kv[(size_t)(rowb+r2)*DM + dv] = f2bf(pr);
          }
        }
      } else {
        #pragma unroll
        for (int r2=0;r2<4;r2++)
          o_f[(size_t)(rowb+r2)*DM + col] = a[r2]*sc;
      }
    }
  }
}

// ---------------- K3: per-chunk sums of kv / max(exp(t*ld),1e-10), CH=32 -----------
__global__ __launch_bounds__(256)
void kv_phase1(const u16* __restrict__ kv, const float* __restrict__ decay,
               float* __restrict__ part)
{
  const int c = blockIdx.x & 127, b = blockIdx.x >> 7;
  const int d0 = threadIdx.x*4;
  float ld[4]; f32x4 sum = {0.f,0.f,0.f,0.f};
  #pragma unroll
  for (int j=0;j<4;j++){
    const float dec = 1.f/(1.f+expf(-decay[d0+j]));
    ld[j] = logf(fmaxf(dec, 1e-7f));
  }
  for (int t=c*32; t<c*32+32; ++t){
    const size_t base = ((size_t)(b*4096 + t))*DM + d0;
    const u16x4 p4 = *(const u16x4*)&kv[base];
    const float tf = (float)t;
    #pragma unroll
    for (int j=0;j<4;j++){
      const float e = expf(tf*ld[j]);                        // underflows to 0 like ref
      sum[j] += bf2f(p4[j]) / fmaxf(e, 1e-10f);
    }
  }
  *(f32x4*)&part[((size_t)(b*128+c))*DM + d0] = sum;
}

// ---------------- K4: exclusive prefix over 128 chunk sums (8-wide pipelined) -------
__global__ void chunk_prefix(float* __restrict__ part){
  const int g = blockIdx.x*256 + threadIdx.x;  // 0..1023
  const int b = g >> 8, d0 = (g & 255)*4;
  f32x4 run = {0.f,0.f,0.f,0.f};
  for (int c8=0; c8<128; c8+=8){
    f32x4 v[8];
    #pragma unroll
    for (int i=0;i<8;i++)
      v[i] = *(const f32x4*)&part[((size_t)(b*128+c8+i))*DM + d0];
    #pragma unroll
    for (int i=0;i<8;i++){
      const f32x4 tmp = v[i];
      *(f32x4*)&part[((size_t)(b*128+c8+i))*DM + d0] = run;
      run += tmp;
    }
  }
}

// ---------------- K5: in-chunk scan + y=r*state + rmsnorm -> yn (CH=32) -------------
__global__ __launch_bounds__(256)
void scan_norm(const u16* __restrict__ kv, const u16* __restrict__ rbuf,
               const float* __restrict__ part, const float* __restrict__ decay,
               const float* __restrict__ lnw, u16* __restrict__ yn)
{
  const int c = blockIdx.x & 127, b = blockIdx.x >> 7;
  const int tid = threadIdx.x, lane = tid&63, wave = tid>>6;
  const int d0 = tid*4;
  __shared__ float red[2][4];
  f32x4 run = *(const f32x4*)&part[((size_t)(b*128+c))*DM + d0];
  float ld[4], lw[4];
  #pragma unroll
  for (int j=0;j<4;j++){
    const float dec = 1.f/(1.f+expf(-decay[d0+j]));
    ld[j] = logf(fmaxf(dec, 1e-7f));
    lw[j] = lnw[d0+j];
  }
  for (int t=c*32; t<c*32+32; ++t){
    const size_t base = ((size_t)(b*4096+t))*DM + d0;
    const u16x4 p4 = *(const u16x4*)&kv[base];
    const u16x4 r4 = *(const u16x4*)&rbuf[base];
    const float tf = (float)t;
    float y[4]; float ss = 0.f;
    #pragma unroll
    for (int j=0;j<4;j++){
      const float e = expf(tf*ld[j]);                        // same expr as kv_phase1
      run[j] += bf2f(p4[j]) / fmaxf(e, 1e-10f);
      const float st = run[j]*e;                             // unclipped, underflows like ref
      y[j] = bf2f(r4[j])*st;
      ss += y[j]*y[j];
    }
    #pragma unroll
    for (int off=32; off; off>>=1) ss += __shfl_down(ss, off);
    if (lane==0) red[t&1][wave] = ss;
    __builtin_amdgcn_s_barrier();
    const float tot = (red[t&1][0]+red[t&1][1])+(red[t&1][2]+red[t&1][3]);
    const float rs = 1.f/sqrtf(tot*(1.f/1024.f) + 1e-6f);
    u16x4 o;
    #pragma unroll
    for (int j=0;j<4;j++) o[j] = f2bf(y[j]*rs*lw[j]);
    *(u16x4*)&yn[base] = o;
  }
}

extern "C" void kernel_launch(void* const* d_in, const int* in_sizes, int n_in,
                              void* d_out, int out_size, void* d_ws, size_t ws_size,
                              hipStream_t stream)
{
  (void)in_sizes; (void)n_in; (void)out_size; (void)ws_size;
  const float* x    = (const float*)d_in[0];
  const float* Wr   = (const float*)d_in[1];
  const float* Wk   = (const float*)d_in[2];
  const float* Wv   = (const float*)d_in[3];
  const float* Wo   = (const float*)d_in[4];
  const float* dec  = (const float*)d_in[5];
  const float* lnw  = (const float*)d_in[6];

  // layout: wq 8MB | wsc | rbuf 33.5MB | kvbuf 33.5MB | part 2MB | xb 33.5MB | yn 33.5MB
  char* ws = (char*)d_ws;
  u16*   wq     = (u16*)(ws + 0);
  float* wsc    = (float*)(ws + 8388608);
  u16*   rbuf   = (u16*)(ws + 8404992);
  u16*   kvbuf  = (u16*)(ws + 41959424);
  float* part   = (float*)(ws + 75513856);    // 2MB
  u16*   xb     = (u16*)(ws + 77611008);
  u16*   yn     = (u16*)(ws + 111165440);     // ends 144,719,872

  quantize_w<<<1024, 256, 0, stream>>>(Wr, Wk, Wv, Wo, wq, wsc);
  cvt_x<<<16384, 256, 0, stream>>>(x, xb);
  gemm_s<0><<<dim3(128,24), 256, 0, stream>>>(xb, wq, wsc, rbuf, kvbuf, nullptr);
  kv_phase1<<<512, 256, 0, stream>>>(kvbuf, dec, part);
  chunk_prefix<<<4, 256, 0, stream>>>(part);
  scan_norm<<<512, 256, 0, stream>>>(kvbuf, rbuf, part, dec, lnw, yn);
  gemm_s<1><<<dim3(128,8), 256, 0, stream>>>(yn, wq + 3*1024*1024, wsc + 3072,
                                             nullptr, nullptr, (float*)d_out);
}

// Round 9
// 221.648 us; speedup vs baseline: 2.1030x; 1.0926x over previous
//
#include <hip/hip_runtime.h>

typedef unsigned short u16;
typedef __attribute__((ext_vector_type(8))) short bf16x8;
typedef __attribute__((ext_vector_type(4))) float f32x4;
typedef __attribute__((ext_vector_type(4))) int   i32x4;
typedef __attribute__((ext_vector_type(4))) unsigned short u16x4;

#define DM 1024

__device__ __forceinline__ float bf2f(u16 u){
  union { unsigned int i; float f; } v; v.i = ((unsigned int)u)<<16; return v.f;
}
__device__ __forceinline__ u16 f2bf(float f){
  unsigned int x = __float_as_uint(f);
  return (u16)((x + 0x7FFFu + ((x>>16)&1u)) >> 16);   // RNE, finite inputs only
}

// ---------------- K0: ternary-quantize ----------------
// wq (bf16) rows: [0,1024) = R ; [1024,3072) = K[d],V[d] interleaved.
// wq8 (i8)  rows: [0,1024) = O (ternary is exact in i8).  wsc: all 4096 rows.
__global__ __launch_bounds__(256)
void quantize_w(const float* __restrict__ W0, const float* __restrict__ W1,
                const float* __restrict__ W2, const float* __restrict__ W3,
                u16* __restrict__ wq, signed char* __restrict__ wq8,
                float* __restrict__ wsc)
{
  const int gr   = blockIdx.x*4 + (threadIdx.x>>6);  // output row 0..4095 (wave-uniform)
  const int lane = threadIdx.x & 63;
  const float* W; int row;
  if (gr < 1024)      { W = W0; row = gr; }
  else if (gr < 3072) { row = (gr-1024)>>1; W = (gr&1) ? W2 : W1; }
  else                { W = W3; row = gr-3072; }
  const float* wr = W + (size_t)row*DM;
  float4 v[4]; float s = 0.f;
  #pragma unroll
  for (int c=0;c<4;c++){
    v[c] = *(const float4*)&wr[c*256 + lane*4];
    s += fabsf(v[c].x)+fabsf(v[c].y)+fabsf(v[c].z)+fabsf(v[c].w);
  }
  #pragma unroll
  for (int off=32; off; off>>=1) s += __shfl_down(s, off);
  s = __shfl(s, 0);
  const float scale = fmaxf(s*(1.f/1024.f), 1e-5f);
  if (lane==0) wsc[gr] = scale;
  if (gr < 3072){
    u16* wo = wq + (size_t)gr*DM;
    #pragma unroll
    for (int c=0;c<4;c++){
      u16x4 q;
      q[0] = f2bf(fminf(fmaxf(rintf(v[c].x/scale),-1.f),1.f));
      q[1] = f2bf(fminf(fmaxf(rintf(v[c].y/scale),-1.f),1.f));
      q[2] = f2bf(fminf(fmaxf(rintf(v[c].z/scale),-1.f),1.f));
      q[3] = f2bf(fminf(fmaxf(rintf(v[c].w/scale),-1.f),1.f));
      *(u16x4*)&wo[c*256 + lane*4] = q;
    }
  } else {
    signed char* wo = wq8 + (size_t)(gr-3072)*DM;
    #pragma unroll
    for (int c=0;c<4;c++){
      const int q0 = (int)rintf(fminf(fmaxf(v[c].x/scale,-1.f),1.f));
      const int q1 = (int)rintf(fminf(fmaxf(v[c].y/scale,-1.f),1.f));
      const int q2 = (int)rintf(fminf(fmaxf(v[c].z/scale,-1.f),1.f));
      const int q3 = (int)rintf(fminf(fmaxf(v[c].w/scale,-1.f),1.f));
      const unsigned int p = (q0&0xFF) | ((q1&0xFF)<<8) | ((q2&0xFF)<<16) | ((unsigned)(q3&0xFF)<<24);
      *(unsigned int*)&wo[c*256 + lane*4] = p;
    }
  }
}

// ---------------- K1: x f32 -> bf16 ----------------
__global__ void cvt_x(const float* __restrict__ x, u16* __restrict__ xb){
  const int i = (blockIdx.x*256 + threadIdx.x)*4;
  float4 v = *(const float4*)&x[i];
  u16x4 o; o[0]=f2bf(v.x); o[1]=f2bf(v.y); o[2]=f2bf(v.z); o[3]=f2bf(v.w);
  *(u16x4*)&xb[i] = o;
}

// ---------------- K2: m97-style 128x128 single-buffer bf16 GEMM (912 TF, R8) --------
// N=3072; cols<1024 -> sigmoid -> r ; cols>=1024 interleaved k/v -> kv product.
#define RD(base, off) (*(const bf16x8*)((const char*)(base) + (off)))

__global__ __launch_bounds__(256, 4)
void gemm_rkv(const u16* __restrict__ Ag, const u16* __restrict__ Bq,
              const float* __restrict__ bscale,
              u16* __restrict__ o_r, u16* __restrict__ o_kv)
{
  __shared__ u16 sA[128*64];
  __shared__ u16 sB[128*64];
  const int tid = threadIdx.x, wave = tid>>6, lane = tid&63;
  const int lr = lane&15, lg = lane>>4;
  const int wm = wave>>1, wn = wave&1;
  const int bm0 = blockIdx.x*128, bn0 = blockIdx.y*128;
  constexpr int nt = 16;

  const int r8   = lane>>3;
  const int scol = ((lane&7)<<4) ^ (r8<<4);
  const size_t aoff = (size_t)(bm0 + wave*8 + r8)*2048 + scol;
  const size_t boff = (size_t)(bn0 + wave*8 + r8)*2048 + scol;
  const int ldst = wave*1024;

  const int S = (lr&7)<<4;
  const int koff0 = ((lg<<4)     ) ^ S;
  const int koff1 = (64 + (lg<<4)) ^ S;
  const int arow = (wm*64 + lr)*128;
  const int brow = (wn*64 + lr)*128;

  f32x4 acc[4][4];
  #pragma unroll
  for (int i=0;i<4;i++)
    #pragma unroll
    for (int j=0;j<4;j++) acc[i][j] = (f32x4){0.f,0.f,0.f,0.f};

  for (int t=0; t<nt; ++t){
    #pragma unroll
    for (int q=0;q<4;q++){
      __builtin_amdgcn_global_load_lds(
        (const __attribute__((address_space(1))) void*)((const char*)Ag + aoff + q*65536 + (size_t)t*128),
        (__attribute__((address_space(3))) void*)((char*)sA + ldst + q*4096), 16, 0, 0);
      __builtin_amdgcn_global_load_lds(
        (const __attribute__((address_space(1))) void*)((const char*)Bq + boff + q*65536 + (size_t)t*128),
        (__attribute__((address_space(3))) void*)((char*)sB + ldst + q*4096), 16, 0, 0);
    }
    __syncthreads();
    {
      bf16x8 a[4], b[4];
      #pragma unroll
      for (int m=0;m<4;m++) a[m] = RD(sA, arow + m*2048 + koff0);
      #pragma unroll
      for (int n=0;n<4;n++) b[n] = RD(sB, brow + n*2048 + koff0);
      #pragma unroll
      for (int m=0;m<4;m++)
        #pragma unroll
        for (int n=0;n<4;n++)
          acc[m][n] = __builtin_amdgcn_mfma_f32_16x16x32_bf16(a[m], b[n], acc[m][n], 0,0,0);
      #pragma unroll
      for (int m=0;m<4;m++) a[m] = RD(sA, arow + m*2048 + koff1);
      #pragma unroll
      for (int n=0;n<4;n++) b[n] = RD(sB, brow + n*2048 + koff1);
      #pragma unroll
      for (int m=0;m<4;m++)
        #pragma unroll
        for (int n=0;n<4;n++)
          acc[m][n] = __builtin_amdgcn_mfma_f32_16x16x32_bf16(a[m], b[n], acc[m][n], 0,0,0);
    }
    __syncthreads();
  }

  #pragma unroll
  for (int mi=0; mi<4; ++mi){
    #pragma unroll
    for (int ni=0; ni<4; ++ni){
      const int col = bn0 + wn*64 + ni*16 + lr;
      const float sc = bscale[col];
      const int rowb = bm0 + wm*64 + mi*16 + lg*4;
      const f32x4 a = acc[mi][ni];
      if (bn0 < 1024){
        #pragma unroll
        for (int r2=0;r2<4;r2++){
          const float val = a[r2]*sc;
          o_r[(size_t)(rowb+r2)*DM + col] = f2bf(1.f/(1.f+expf(-val)));
        }
      } else {
        const int dv = (col - 1024) >> 1;
        #pragma unroll
        for (int r2=0;r2<4;r2++){
          const float val = a[r2]*sc;
          const float pr  = val * __shfl_xor(val, 1);
          if (!(lr & 1))
            o_kv[(size_t)(rowb+r2)*DM + dv] = f2bf(pr);
        }
      }
    }
  }
}

// ---------------- K6: i8 GEMM for the Wo projection (2x MFMA rate, exact i32 acc) ----
// A = yn8 (per-row scale sxr), B = wq8 ternary. K=1024 i8 -> row 1024B, 8 tiles x 128B.
// Staging/swizzle bytes identical to gemm_rkv; A-frag k = 16*(lane>>4)+j.
#define RD8(base, off) (*(const i32x4*)((const char*)(base) + (off)))

__global__ __launch_bounds__(256, 4)
void gemm_o8(const signed char* __restrict__ Ag, const signed char* __restrict__ Bq,
             const float* __restrict__ bscale, const float* __restrict__ sxr,
             float* __restrict__ o_f)
{
  __shared__ signed char sA[128*128];           // 16KB
  __shared__ signed char sB[128*128];           // 16KB
  const int tid = threadIdx.x, wave = tid>>6, lane = tid&63;
  const int lr = lane&15, lg = lane>>4;
  const int wm = wave>>1, wn = wave&1;
  const int bm0 = blockIdx.x*128, bn0 = blockIdx.y*128;
  constexpr int nt = 8;                         // K = 1024 i8 / 128B

  const int r8   = lane>>3;
  const int scol = ((lane&7)<<4) ^ (r8<<4);
  const size_t aoff = (size_t)(bm0 + wave*8 + r8)*1024 + scol;
  const size_t boff = (size_t)(bn0 + wave*8 + r8)*1024 + scol;
  const int ldst = wave*1024;

  const int S = (lr&7)<<4;
  const int koff0 = ((lg<<4)     ) ^ S;         // ks0: bytes [0,64)
  const int koff1 = (64 + (lg<<4)) ^ S;         // ks1: bytes [64,128)
  const int arow = (wm*64 + lr)*128;
  const int brow = (wn*64 + lr)*128;

  i32x4 acc[4][4];
  #pragma unroll
  for (int i=0;i<4;i++)
    #pragma unroll
    for (int j=0;j<4;j++) acc[i][j] = (i32x4){0,0,0,0};

  for (int t=0; t<nt; ++t){
    #pragma unroll
    for (int q=0;q<4;q++){
      __builtin_amdgcn_global_load_lds(
        (const __attribute__((address_space(1))) void*)((const char*)Ag + aoff + q*32768 + (size_t)t*128),
        (__attribute__((address_space(3))) void*)((char*)sA + ldst + q*4096), 16, 0, 0);
      __builtin_amdgcn_global_load_lds(
        (const __attribute__((address_space(1))) void*)((const char*)Bq + boff + q*32768 + (size_t)t*128),
        (__attribute__((address_space(3))) void*)((char*)sB + ldst + q*4096), 16, 0, 0);
    }
    __syncthreads();
    {
      i32x4 a[4], b[4];
      #pragma unroll
      for (int m=0;m<4;m++) a[m] = RD8(sA, arow + m*2048 + koff0);
      #pragma unroll
      for (int n=0;n<4;n++) b[n] = RD8(sB, brow + n*2048 + koff0);
      #pragma unroll
      for (int m=0;m<4;m++)
        #pragma unroll
        for (int n=0;n<4;n++)
          acc[m][n] = __builtin_amdgcn_mfma_i32_16x16x64_i8(a[m], b[n], acc[m][n], 0,0,0);
      #pragma unroll
      for (int m=0;m<4;m++) a[m] = RD8(sA, arow + m*2048 + koff1);
      #pragma unroll
      for (int n=0;n<4;n++) b[n] = RD8(sB, brow + n*2048 + koff1);
      #pragma unroll
      for (int m=0;m<4;m++)
        #pragma unroll
        for (int n=0;n<4;n++)
          acc[m][n] = __builtin_amdgcn_mfma_i32_16x16x64_i8(a[m], b[n], acc[m][n], 0,0,0);
    }
    __syncthreads();
  }

  #pragma unroll
  for (int mi=0; mi<4; ++mi){
    const int rowb = bm0 + wm*64 + mi*16 + lg*4;
    float sx[4];
    #pragma unroll
    for (int r2=0;r2<4;r2++) sx[r2] = sxr[rowb+r2];
    #pragma unroll
    for (int ni=0; ni<4; ++ni){
      const int col = bn0 + wn*64 + ni*16 + lr;
      const float sc = bscale[col];
      const i32x4 a = acc[mi][ni];
      #pragma unroll
      for (int r2=0;r2<4;r2++)
        o_f[(size_t)(rowb+r2)*DM + col] = (float)a[r2] * sx[r2] * sc;
    }
  }
}

// ---------------- K3: per-chunk sums of kv / max(exp(t*ld),1e-10), CH=32 -----------
__global__ __launch_bounds__(256)
void kv_phase1(const u16* __restrict__ kv, const float* __restrict__ decay,
               float* __restrict__ part)
{
  const int c = blockIdx.x & 127, b = blockIdx.x >> 7;
  const int d0 = threadIdx.x*4;
  float ld[4]; f32x4 sum = {0.f,0.f,0.f,0.f};
  #pragma unroll
  for (int j=0;j<4;j++){
    const float dec = 1.f/(1.f+expf(-decay[d0+j]));
    ld[j] = logf(fmaxf(dec, 1e-7f));
  }
  for (int t=c*32; t<c*32+32; ++t){
    const size_t base = ((size_t)(b*4096 + t))*DM + d0;
    const u16x4 p4 = *(const u16x4*)&kv[base];
    const float tf = (float)t;
    #pragma unroll
    for (int j=0;j<4;j++){
      const float e = expf(tf*ld[j]);                        // underflows to 0 like ref
      sum[j] += bf2f(p4[j]) / fmaxf(e, 1e-10f);
    }
  }
  *(f32x4*)&part[((size_t)(b*128+c))*DM + d0] = sum;
}

// ---------------- K4: exclusive prefix over 128 chunk sums (16 blocks, 1 d/thread) --
__global__ void chunk_prefix(float* __restrict__ part){
  const int g = blockIdx.x*256 + threadIdx.x;  // 0..4095
  const int b = g >> 10, d = g & 1023;
  float run = 0.f;
  for (int c8=0; c8<128; c8+=8){
    float v[8];
    #pragma unroll
    for (int i=0;i<8;i++)
      v[i] = part[((size_t)(b*128+c8+i))*DM + d];
    #pragma unroll
    for (int i=0;i<8;i++){
      const float tmp = v[i];
      part[((size_t)(b*128+c8+i))*DM + d] = run;
      run += tmp;
    }
  }
}

// ---------------- K5: scan + y=r*state + rmsnorm -> i8 yn (per-row scale) -----------
// q = rint(y*lw * 127/m1), sxr = m1*rs/127  (rs cancels; one barrier for both sums)
__global__ __launch_bounds__(256)
void scan_norm(const u16* __restrict__ kv, const u16* __restrict__ rbuf,
               const float* __restrict__ part, const float* __restrict__ decay,
               const float* __restrict__ lnw, signed char* __restrict__ yn8,
               float* __restrict__ sxr)
{
  const int c = blockIdx.x & 127, b = blockIdx.x >> 7;
  const int tid = threadIdx.x, lane = tid&63, wave = tid>>6;
  const int d0 = tid*4;
  __shared__ float redS[2][4];
  __shared__ float redM[2][4];
  f32x4 run = *(const f32x4*)&part[((size_t)(b*128+c))*DM + d0];
  float ld[4], lw[4];
  #pragma unroll
  for (int j=0;j<4;j++){
    const float dec = 1.f/(1.f+expf(-decay[d0+j]));
    ld[j] = logf(fmaxf(dec, 1e-7f));
    lw[j] = lnw[d0+j];
  }
  for (int t=c*32; t<c*32+32; ++t){
    const size_t base = ((size_t)(b*4096+t))*DM + d0;
    const u16x4 p4 = *(const u16x4*)&kv[base];
    const u16x4 r4 = *(const u16x4*)&rbuf[base];
    const float tf = (float)t;
    float yl[4]; float ss = 0.f, mx = 0.f;
    #pragma unroll
    for (int j=0;j<4;j++){
      const float e = expf(tf*ld[j]);                        // same expr as kv_phase1
      run[j] += bf2f(p4[j]) / fmaxf(e, 1e-10f);
      const float st = run[j]*e;                             // unclipped, underflows like ref
      const float y = bf2f(r4[j])*st;
      ss += y*y;
      yl[j] = y*lw[j];
      mx = fmaxf(mx, fabsf(yl[j]));
    }
    #pragma unroll
    for (int off=32; off; off>>=1){
      ss += __shfl_down(ss, off);
      mx  = fmaxf(mx, __shfl_down(mx, off));
    }
    if (lane==0){ redS[t&1][wave] = ss; redM[t&1][wave] = mx; }
    __builtin_amdgcn_s_barrier();
    const float tot = (redS[t&1][0]+redS[t&1][1])+(redS[t&1][2]+redS[t&1][3]);
    const float m1  = fmaxf(fmaxf(redM[t&1][0],redM[t&1][1]),
                            fmaxf(redM[t&1][2],redM[t&1][3]));
    const float rs  = 1.f/sqrtf(tot*(1.f/1024.f) + 1e-6f);
    const float m1s = fmaxf(m1, 1e-30f);
    const float qk  = 127.f/m1s;
    if (tid==0) sxr[b*4096+t] = m1s*rs*(1.f/127.f);
    unsigned int p = 0;
    #pragma unroll
    for (int j=0;j<4;j++){
      int q = (int)rintf(yl[j]*qk);
      q = q>127?127:(q<-127?-127:q);
      p |= ((unsigned)(q&0xFF)) << (8*j);
    }
    *(unsigned int*)&yn8[base] = p;
  }
}

extern "C" void kernel_launch(void* const* d_in, const int* in_sizes, int n_in,
                              void* d_out, int out_size, void* d_ws, size_t ws_size,
                              hipStream_t stream)
{
  (void)in_sizes; (void)n_in; (void)out_size; (void)ws_size;
  const float* x    = (const float*)d_in[0];
  const float* Wr   = (const float*)d_in[1];
  const float* Wk   = (const float*)d_in[2];
  const float* Wv   = (const float*)d_in[3];
  const float* Wo   = (const float*)d_in[4];
  const float* dec  = (const float*)d_in[5];
  const float* lnw  = (const float*)d_in[6];

  // layout: wq 6MB | wq8 1MB | wsc 16KB | rbuf 33.5MB | kvbuf 33.5MB | part 2MB |
  //         xb 33.5MB | yn8 16.8MB | sxr 64KB
  char* ws = (char*)d_ws;
  u16*         wq    = (u16*)(ws + 0);
  signed char* wq8   = (signed char*)(ws + 6291456);
  float*       wsc   = (float*)(ws + 7340032);
  u16*         rbuf  = (u16*)(ws + 7356416);
  u16*         kvbuf = (u16*)(ws + 40910848);
  float*       part  = (float*)(ws + 74465280);
  u16*         xb    = (u16*)(ws + 76562432);
  signed char* yn8   = (signed char*)(ws + 110116864);
  float*       sxr   = (float*)(ws + 126894080);   // ends 126,959,616

  quantize_w<<<1024, 256, 0, stream>>>(Wr, Wk, Wv, Wo, wq, wq8, wsc);
  cvt_x<<<16384, 256, 0, stream>>>(x, xb);
  gemm_rkv<<<dim3(128,24), 256, 0, stream>>>(xb, wq, wsc, rbuf, kvbuf);
  kv_phase1<<<512, 256, 0, stream>>>(kvbuf, dec, part);
  chunk_prefix<<<16, 256, 0, stream>>>(part);
  scan_norm<<<512, 256, 0, stream>>>(kvbuf, rbuf, part, dec, lnw, yn8, sxr);
  gemm_o8<<<dim3(128,8), 256, 0, stream>>>(yn8, wq8, wsc + 3072, sxr, (float*)d_out);
}